// Round 8
// baseline (921.392 us; speedup 1.0000x reference)
//
#include <hip/hip_runtime.h>
#include <hip/hip_fp16.h>

#define DD 192
#define HH 192
#define WW 192
#define NVOX (DD * HH * WW)

// tile 16x16x16, halo 8; fp16 region x32 [-8,+24), y33 [-8,+25), z33 [-8,+25)
#define RSX 32
#define RSY 33
#define RSZ 33
#define ROWD 16                    // dwords per x-row (32 halves)
#define SLABD (RSY * ROWD)         // 528 dwords per z-slab
#define RTOTH (RSX * RSY * RSZ)    // 34848 halves = 69696 B
#define RTOTD (RTOTH / 2)          // 17424 dwords
#define MAXO (RTOTD - SLABD - ROWD - 2)
#define NCHUNK (RTOTH / 8)         // 4356 16-byte DMA chunks
#define NT 512
#define NBLK (12 * 12 * 12)

#define AS1 __attribute__((address_space(1)))
#define AS3 __attribute__((address_space(3)))

// ---- mov fp32 -> fp16 (contiguous, BW-bound) ----
__global__ __launch_bounds__(256) void conv_fp16(
    const float4* __restrict__ in, int4* __restrict__ out)
{
    const int i = blockIdx.x * 256 + threadIdx.x;
    const float4 a = in[2 * i];
    const float4 b = in[2 * i + 1];
    __half2 h0 = __floats2half2_rn(a.x, a.y);
    __half2 h1 = __floats2half2_rn(a.z, a.w);
    __half2 h2 = __floats2half2_rn(b.x, b.y);
    __half2 h3 = __floats2half2_rn(b.z, b.w);
    int4 o;
    o.x = *(int*)&h0; o.y = *(int*)&h1; o.z = *(int*)&h2; o.w = *(int*)&h3;
    out[i] = o;
}

__global__ __launch_bounds__(NT, 4) void warp_mse_ilp(
    const ushort* __restrict__ movh,
    const float* __restrict__ mov,
    const float* __restrict__ vf,
    const float* __restrict__ fix,
    const int* __restrict__ mask,
    const ushort* __restrict__ zbuf,
    float* __restrict__ acc,   // [0]=sum(sq*m), [1]=sum(m), [2]=done ctr
    float* __restrict__ out)
{
    __shared__ ushort smov[RTOTH + 8];
    __shared__ float s_sq[8], s_cnt[8];

    const int tid = threadIdx.x;
    const int bx0 = blockIdx.x * 16, by0 = blockIdx.y * 16, bz0 = blockIdx.z * 16;
    const int x_lo = bx0 - 8, y_lo = by0 - 8, z_lo = bz0 - 8;

    // ---- async DMA staging: fp16 region, OOB chunks redirected to zbuf ----
    #pragma unroll
    for (int i = 0; i < 9; ++i) {
        const int q = tid + i * NT;
        if (q < NCHUNK) {
            const int rz = q / (RSY * 4);
            const int rem = q - rz * (RSY * 4);
            const int ry = rem >> 2;
            const int k  = rem & 3;
            const int gz = z_lo + rz, gy = y_lo + ry, gx = x_lo + 8 * k;
            const bool valid = ((unsigned)gz < DD) & ((unsigned)gy < HH) &
                               ((unsigned)gx < WW);
            const ushort* src = valid ? (movh + ((gz * HH + gy) * WW + gx)) : zbuf;
            const int qb = i * NT + (tid & ~63);
            __builtin_amdgcn_global_load_lds((AS1 void*)src,
                                             (AS3 void*)(smov + 8 * qb), 16, 0, 0);
        }
    }

    // thread -> 8 voxels: x-octet (tid&1), y (tid>>1)&15, z tid>>5
    const int xo = (tid & 1) * 8;
    const int ly = (tid >> 1) & 15;
    const int lz = tid >> 5;
    const int gz = bz0 + lz, gy = by0 + ly, gx0 = bx0 + xo;
    const int base = (gz * HH + gy) * WW + gx0;

    // prefetch streaming inputs (overlaps DMA drain)
    float4 dzg[2], dyg[2], dxg[2], fg[2];
    int4 mg[2];
    #pragma unroll
    for (int g = 0; g < 2; ++g) {
        dzg[g] = *(const float4*)(vf + base + 4 * g);
        dyg[g] = *(const float4*)(vf + NVOX + base + 4 * g);
        dxg[g] = *(const float4*)(vf + 2 * NVOX + base + 4 * g);
        fg[g]  = *(const float4*)(fix + base + 4 * g);
        mg[g]  = *(const int4*)(mask + base + 4 * g);
    }

    __syncthreads();   // staging complete

    const uint* sdw = (const uint*)smov;
    float sq = 0.0f, cnt = 0.0f;

    #pragma unroll
    for (int g = 0; g < 2; ++g) {
        const float dzv[4] = {dzg[g].x, dzg[g].y, dzg[g].z, dzg[g].w};
        const float dyv[4] = {dyg[g].x, dyg[g].y, dyg[g].z, dyg[g].w};
        const float dxv[4] = {dxg[g].x, dxg[g].y, dxg[g].z, dxg[g].w};
        const float fv[4]  = {fg[g].x, fg[g].y, fg[g].z, fg[g].w};
        const int   mv[4]  = {mg[g].x, mg[g].y, mg[g].z, mg[g].w};

        // phase 1: per-voxel addresses, weights, flags
        int   oo[4], z0s[4], y0s[4], x0s[4];
        float wzv[4], wyv[4], wxv[4];
        bool  odd[4], ib[4];
        #pragma unroll
        for (int j = 0; j < 4; ++j) {
            const int gx = gx0 + 4 * g + j;
            const float z = (float)gz + dzv[j];
            const float y = (float)gy + dyv[j];
            const float x = (float)gx + dxv[j];
            const float z0f = floorf(z), y0f = floorf(y), x0f = floorf(x);
            wzv[j] = z - z0f; wyv[j] = y - y0f; wxv[j] = x - x0f;
            const int z0 = (int)z0f, y0 = (int)y0f, x0 = (int)x0f;
            z0s[j] = z0; y0s[j] = y0; x0s[j] = x0;
            const int z0l = z0 - z_lo, y0l = y0 - y_lo, x0l = x0 - x_lo;
            ib[j] = ((unsigned)z0l < RSZ - 1) & ((unsigned)y0l < RSY - 1) &
                    ((unsigned)x0l < RSX - 1);
            odd[j] = (x0l & 1) != 0;
            int o = z0l * SLABD + y0l * ROWD + (x0l >> 1);
            oo[j] = min(max(o, 0), MAXO);   // safe even when !ib
        }

        // phase 2: issue ALL 32 LDS dword reads (4 independent chains)
        uint dw[4][8];
        #pragma unroll
        for (int j = 0; j < 4; ++j) {
            const int o = oo[j];
            dw[j][0] = sdw[o];
            dw[j][1] = sdw[o + 1];
            dw[j][2] = sdw[o + ROWD];
            dw[j][3] = sdw[o + ROWD + 1];
            dw[j][4] = sdw[o + SLABD];
            dw[j][5] = sdw[o + SLABD + 1];
            dw[j][6] = sdw[o + SLABD + ROWD];
            dw[j][7] = sdw[o + SLABD + ROWD + 1];
        }

        // phase 3: decode corners
        float v[4][8];
        #pragma unroll
        for (int j = 0; j < 4; ++j) {
            auto pr = [&](uint A, uint B, float& l, float& r) {
                const float2 fa = __half22float2(*(const __half2*)&A);
                const float fb = __low2float(*(const __half2*)&B);
                l = odd[j] ? fa.y : fa.x;
                r = odd[j] ? fb   : fa.y;
            };
            pr(dw[j][0], dw[j][1], v[j][0], v[j][1]);
            pr(dw[j][2], dw[j][3], v[j][2], v[j][3]);
            pr(dw[j][4], dw[j][5], v[j][4], v[j][5]);
            pr(dw[j][6], dw[j][7], v[j][6], v[j][7]);
        }

        // batched fallback: one divergent burst per group
        bool anyfb = !(ib[0] & ib[1] & ib[2] & ib[3]);
        if (anyfb) {
            #pragma unroll
            for (int j = 0; j < 4; ++j) {
                if (!ib[j]) {
                    const int z0 = z0s[j], y0 = y0s[j], x0 = x0s[j];
                    const int z1 = z0 + 1, y1 = y0 + 1, x1 = x0 + 1;
                    const bool zi0 = (unsigned)z0 < DD, zi1 = (unsigned)z1 < DD;
                    const bool yi0 = (unsigned)y0 < HH, yi1 = (unsigned)y1 < HH;
                    const bool xi0 = (unsigned)x0 < WW, xi1 = (unsigned)x1 < WW;
                    auto ld = [&](int iz, int iy, int ix, bool ok) -> float {
                        return ok ? mov[(iz * HH + iy) * WW + ix] : 0.0f;
                    };
                    v[j][0] = ld(z0, y0, x0, zi0 & yi0 & xi0);
                    v[j][1] = ld(z0, y0, x1, zi0 & yi0 & xi1);
                    v[j][2] = ld(z0, y1, x0, zi0 & yi1 & xi0);
                    v[j][3] = ld(z0, y1, x1, zi0 & yi1 & xi1);
                    v[j][4] = ld(z1, y0, x0, zi1 & yi0 & xi0);
                    v[j][5] = ld(z1, y0, x1, zi1 & yi0 & xi1);
                    v[j][6] = ld(z1, y1, x0, zi1 & yi1 & xi0);
                    v[j][7] = ld(z1, y1, x1, zi1 & yi1 & xi1);
                }
            }
        }

        // phase 4: lerp + accumulate
        #pragma unroll
        for (int j = 0; j < 4; ++j) {
            const float wx = wxv[j], wy = wyv[j], wz = wzv[j];
            const float c00 = v[j][0] + (v[j][1] - v[j][0]) * wx;
            const float c01 = v[j][2] + (v[j][3] - v[j][2]) * wx;
            const float c10 = v[j][4] + (v[j][5] - v[j][4]) * wx;
            const float c11 = v[j][6] + (v[j][7] - v[j][6]) * wx;
            const float c0 = c00 + (c01 - c00) * wy;
            const float c1 = c10 + (c11 - c10) * wy;
            const float warped = c0 + (c1 - c0) * wz;
            const float m = (mv[j] != 0) ? 1.0f : 0.0f;
            const float diff = warped - fv[j];
            sq += diff * diff * m;
            cnt += m;
        }
    }

    // ---- reduction: wave64 shuffle -> LDS -> one atomic pair per block ----
    #pragma unroll
    for (int off = 32; off > 0; off >>= 1) {
        sq  += __shfl_down(sq, off, 64);
        cnt += __shfl_down(cnt, off, 64);
    }
    const int lane = tid & 63;
    const int wid = tid >> 6;   // 0..7
    if (lane == 0) { s_sq[wid] = sq; s_cnt[wid] = cnt; }
    __syncthreads();
    if (tid == 0) {
        float bsq = 0.0f, bcnt = 0.0f;
        #pragma unroll
        for (int i = 0; i < 8; ++i) { bsq += s_sq[i]; bcnt += s_cnt[i]; }
        atomicAdd(&acc[0], bsq);
        atomicAdd(&acc[1], bcnt);
        __threadfence();
        const unsigned old = atomicAdd((unsigned*)&acc[2], 1u);
        if (old == NBLK - 1) {
            __threadfence();
            const float s = atomicAdd(&acc[0], 0.0f);
            const float c = atomicAdd(&acc[1], 0.0f);
            out[0] = s / fmaxf(c, 1.0f);
        }
    }
}

// ---- emergency fallback (ws too small): simple per-voxel kernel ----
__global__ __launch_bounds__(256) void warp_mse_simple(
    const float* __restrict__ mov, const float* __restrict__ vf,
    const float* __restrict__ fix, const int* __restrict__ mask,
    float* __restrict__ acc)
{
    const int idx = blockIdx.x * 256 + threadIdx.x;
    float sq = 0.0f, cnt = 0.0f;
    if (idx < NVOX) {
        const int w = idx % WW;
        const int t = idx / WW;
        const int h = t % HH;
        const int d = t / HH;
        const float z = (float)d + vf[idx];
        const float y = (float)h + vf[NVOX + idx];
        const float x = (float)w + vf[2 * NVOX + idx];
        const float z0f = floorf(z), y0f = floorf(y), x0f = floorf(x);
        const float wz = z - z0f, wy = y - y0f, wx = x - x0f;
        const int z0 = (int)z0f, y0 = (int)y0f, x0 = (int)x0f;
        const int z1 = z0 + 1, y1 = y0 + 1, x1 = x0 + 1;
        const bool zi0 = (unsigned)z0 < DD, zi1 = (unsigned)z1 < DD;
        const bool yi0 = (unsigned)y0 < HH, yi1 = (unsigned)y1 < HH;
        const bool xi0 = (unsigned)x0 < WW, xi1 = (unsigned)x1 < WW;
        auto ld = [&](int iz, int iy, int ix, bool ok) -> float {
            return ok ? mov[(iz * HH + iy) * WW + ix] : 0.0f;
        };
        const float v000 = ld(z0, y0, x0, zi0 & yi0 & xi0);
        const float v001 = ld(z0, y0, x1, zi0 & yi0 & xi1);
        const float v010 = ld(z0, y1, x0, zi0 & yi1 & xi0);
        const float v011 = ld(z0, y1, x1, zi0 & yi1 & xi1);
        const float v100 = ld(z1, y0, x0, zi1 & yi0 & xi0);
        const float v101 = ld(z1, y0, x1, zi1 & yi0 & xi1);
        const float v110 = ld(z1, y1, x0, zi1 & yi1 & xi0);
        const float v111 = ld(z1, y1, x1, zi1 & yi1 & xi1);
        const float c00 = v000 + (v001 - v000) * wx;
        const float c01 = v010 + (v011 - v010) * wx;
        const float c10 = v100 + (v101 - v100) * wx;
        const float c11 = v110 + (v111 - v110) * wx;
        const float c0 = c00 + (c01 - c00) * wy;
        const float c1 = c10 + (c11 - c10) * wy;
        const float warped = c0 + (c1 - c0) * wz;
        const float m = (mask[idx] != 0) ? 1.0f : 0.0f;
        const float diff = warped - fix[idx];
        sq = diff * diff * m;
        cnt = m;
    }
    #pragma unroll
    for (int off = 32; off > 0; off >>= 1) {
        sq  += __shfl_down(sq, off, 64);
        cnt += __shfl_down(cnt, off, 64);
    }
    __shared__ float s_sq[4], s_cnt[4];
    const int lane = threadIdx.x & 63, wid = threadIdx.x >> 6;
    if (lane == 0) { s_sq[wid] = sq; s_cnt[wid] = cnt; }
    __syncthreads();
    if (threadIdx.x == 0) {
        atomicAdd(&acc[0], s_sq[0] + s_sq[1] + s_sq[2] + s_sq[3]);
        atomicAdd(&acc[1], s_cnt[0] + s_cnt[1] + s_cnt[2] + s_cnt[3]);
    }
}

__global__ void warp_mse_finalize(const float* __restrict__ acc, float* __restrict__ out) {
    out[0] = acc[0] / fmaxf(acc[1], 1.0f);
}

extern "C" void kernel_launch(void* const* d_in, const int* in_sizes, int n_in,
                              void* d_out, int out_size, void* d_ws, size_t ws_size,
                              hipStream_t stream) {
    const float* mov  = (const float*)d_in[0];
    const float* vf   = (const float*)d_in[1];
    const float* fix  = (const float*)d_in[2];
    const int*   mask = (const int*)d_in[3];
    float* acc = (float*)d_ws;
    float* out = (float*)d_out;

    // [0,16): acc; [64,80): zero DMA source; [256,...): movh
    hipMemsetAsync(d_ws, 0, 256, stream);

    const size_t need = 256 + (size_t)NVOX * 2;
    if (ws_size >= need) {
        ushort* movh = (ushort*)((char*)d_ws + 256);
        const ushort* zbuf = (const ushort*)((char*)d_ws + 64);
        conv_fp16<<<NVOX / (256 * 8), 256, 0, stream>>>(
            (const float4*)mov, (int4*)movh);
        dim3 grid(12, 12, 12);
        warp_mse_ilp<<<grid, NT, 0, stream>>>(movh, mov, vf, fix, mask, zbuf,
                                              acc, out);
    } else {
        warp_mse_simple<<<(NVOX + 255) / 256, 256, 0, stream>>>(mov, vf, fix, mask, acc);
        warp_mse_finalize<<<1, 1, 0, stream>>>(acc, out);
    }
}

// Round 9
// 243.979 us; speedup vs baseline: 3.7765x; 3.7765x over previous
//
#include <hip/hip_runtime.h>
#include <hip/hip_fp16.h>

#define DD 192
#define HH 192
#define WW 192
#define NVOX (DD * HH * WW)

// 16x16x16 tiles, halo 8: fp16 region x32 [-8,+24), y33 [-8,+25), z33 [-8,+25)
#define RSX 32
#define RSY 33
#define RSZ 33
#define ROWD 16                    // dwords per x-row (32 halves)
#define SLABD (RSY * ROWD)         // 528 dwords per z-slab
#define RTOTH (RSX * RSY * RSZ)    // 34848 halves = 69696 B per buffer
#define RTOTD (RTOTH / 2)
#define MAXO (RTOTD - SLABD - ROWD - 2)
#define NCHUNK (RTOTH / 8)         // 4356 16B DMA chunks
#define CHSLAB (RSY * 4)           // 132 chunks per z-slab
#define NT 1024
#define NTILE 1728                 // 12^3
#define GRID 256                   // persistent: 1 block per CU

#define AS1 __attribute__((address_space(1)))
#define AS3 __attribute__((address_space(3)))

// ---- mov fp32 -> fp16 (contiguous, BW-bound, runs once per launch) ----
__global__ __launch_bounds__(256) void conv_fp16(
    const float4* __restrict__ in, int4* __restrict__ out)
{
    const int i = blockIdx.x * 256 + threadIdx.x;
    const float4 a = in[2 * i];
    const float4 b = in[2 * i + 1];
    __half2 h0 = __floats2half2_rn(a.x, a.y);
    __half2 h1 = __floats2half2_rn(a.z, a.w);
    __half2 h2 = __floats2half2_rn(b.x, b.y);
    __half2 h3 = __floats2half2_rn(b.z, b.w);
    int4 o;
    o.x = *(int*)&h0; o.y = *(int*)&h1; o.z = *(int*)&h2; o.w = *(int*)&h3;
    out[i] = o;
}

struct Streams { float4 dz, dy, dx, f; int4 m; };

__device__ __forceinline__ void tile_coords(int n, int& tx, int& ty, int& tz) {
    tx = n / 144;
    const int r = n - tx * 144;
    ty = r / 12;
    tz = r - ty * 12;
}

// issue async DMA of one tile's fp16 region; OOB chunks redirected to zbuf
__device__ __forceinline__ void stage_tile(
    const ushort* __restrict__ movh, const ushort* __restrict__ zbuf,
    uint* sbufd, int x_lo, int y_lo, int z_lo, int tid)
{
    ushort* sbuf = (ushort*)sbufd;
    #pragma unroll
    for (int i = 0; i < 5; ++i) {
        const int q = tid + i * NT;
        if (q < NCHUNK) {
            const int rz = q / CHSLAB;
            const int rem = q - rz * CHSLAB;
            const int ry = rem >> 2;
            const int k  = rem & 3;
            const int gz = z_lo + rz, gy = y_lo + ry, gx = x_lo + 8 * k;
            const bool valid = ((unsigned)gz < DD) & ((unsigned)gy < HH) &
                               ((unsigned)gx < WW);
            const ushort* src = valid ? (movh + ((gz * HH + gy) * WW + gx)) : zbuf;
            const int qb = i * NT + (tid & ~63);    // wave-uniform chunk base
            __builtin_amdgcn_global_load_lds((AS1 void*)src,
                                             (AS3 void*)(sbuf + 8 * qb), 16, 0, 0);
        }
    }
}

__device__ __forceinline__ Streams prefetch_streams(
    const float* __restrict__ vf, const float* __restrict__ fix,
    const int* __restrict__ mask, int base)
{
    Streams s;
    s.dz = *(const float4*)(vf + base);
    s.dy = *(const float4*)(vf + NVOX + base);
    s.dx = *(const float4*)(vf + 2 * NVOX + base);
    s.f  = *(const float4*)(fix + base);
    s.m  = *(const int4*)(mask + base);
    return s;
}

// trilinear sample one voxel from the fp16 LDS buffer (R5/R7-proven structure)
__device__ __forceinline__ void sample_accum(
    const uint* sdw, const float* __restrict__ mov,
    int gz, int gy, int gx, float dz, float dy, float dx,
    float f, int m, int x_lo, int y_lo, int z_lo,
    float& sq, float& cnt)
{
    const float z = (float)gz + dz, y = (float)gy + dy, x = (float)gx + dx;
    const float z0f = floorf(z), y0f = floorf(y), x0f = floorf(x);
    const float wz = z - z0f, wy = y - y0f, wx = x - x0f;
    const int z0 = (int)z0f, y0 = (int)y0f, x0 = (int)x0f;
    const int z0l = z0 - z_lo, y0l = y0 - y_lo, x0l = x0 - x_lo;
    const bool inbox = ((unsigned)z0l < RSZ - 1) & ((unsigned)y0l < RSY - 1) &
                       ((unsigned)x0l < RSX - 1);

    float v000, v001, v010, v011, v100, v101, v110, v111;
    if (inbox) {
        const int o = z0l * SLABD + y0l * ROWD + (x0l >> 1);
        const bool odd = (x0l & 1) != 0;
        const uint a00 = sdw[o];
        const uint b00 = sdw[o + 1];
        const uint a01 = sdw[o + ROWD];
        const uint b01 = sdw[o + ROWD + 1];
        const uint a10 = sdw[o + SLABD];
        const uint b10 = sdw[o + SLABD + 1];
        const uint a11 = sdw[o + SLABD + ROWD];
        const uint b11 = sdw[o + SLABD + ROWD + 1];
        auto pr = [&](uint A, uint B, float& l, float& r) {
            const float2 fa = __half22float2(*(const __half2*)&A);
            const float fb = __low2float(*(const __half2*)&B);
            l = odd ? fa.y : fa.x;
            r = odd ? fb   : fa.y;
        };
        pr(a00, b00, v000, v001);
        pr(a01, b01, v010, v011);
        pr(a10, b10, v100, v101);
        pr(a11, b11, v110, v111);
    } else {
        // rare: beyond halo — fp32 global fallback
        const int z1 = z0 + 1, y1 = y0 + 1, x1 = x0 + 1;
        const bool zi0 = (unsigned)z0 < DD, zi1 = (unsigned)z1 < DD;
        const bool yi0 = (unsigned)y0 < HH, yi1 = (unsigned)y1 < HH;
        const bool xi0 = (unsigned)x0 < WW, xi1 = (unsigned)x1 < WW;
        auto ld = [&](int iz, int iy, int ix, bool ok) -> float {
            return ok ? mov[(iz * HH + iy) * WW + ix] : 0.0f;
        };
        v000 = ld(z0, y0, x0, zi0 & yi0 & xi0);
        v001 = ld(z0, y0, x1, zi0 & yi0 & xi1);
        v010 = ld(z0, y1, x0, zi0 & yi1 & xi0);
        v011 = ld(z0, y1, x1, zi0 & yi1 & xi1);
        v100 = ld(z1, y0, x0, zi1 & yi0 & xi0);
        v101 = ld(z1, y0, x1, zi1 & yi0 & xi1);
        v110 = ld(z1, y1, x0, zi1 & yi1 & xi0);
        v111 = ld(z1, y1, x1, zi1 & yi1 & xi1);
    }

    const float c00 = v000 + (v001 - v000) * wx;
    const float c01 = v010 + (v011 - v010) * wx;
    const float c10 = v100 + (v101 - v100) * wx;
    const float c11 = v110 + (v111 - v110) * wx;
    const float c0 = c00 + (c01 - c00) * wy;
    const float c1 = c10 + (c11 - c10) * wy;
    const float warped = c0 + (c1 - c0) * wz;

    const float mm = (m != 0) ? 1.0f : 0.0f;
    const float diff = warped - f;
    sq += diff * diff * mm;
    cnt += mm;
}

// ---- persistent pipelined kernel: ~7 tiles/block, double-buffered LDS ----
__global__ __launch_bounds__(NT) void warp_mse_persist(
    const ushort* __restrict__ movh,
    const float* __restrict__ mov,
    const float* __restrict__ vf,
    const float* __restrict__ fix,
    const int* __restrict__ mask,
    const ushort* __restrict__ zbuf,
    float* __restrict__ acc,   // [0]=sum(sq*m), [1]=sum(m), [2]=done ctr
    float* __restrict__ out)
{
    __shared__ uint sbufd[2][RTOTD];   // 2 x 69.7 KB fp16 regions
    __shared__ float s_sq[16], s_cnt[16];

    const int tid = threadIdx.x;
    const int b = blockIdx.x;
    // blocks 0..191: 7 tiles; 192..255: 6 tiles (tile order: z fastest -> L2 reuse)
    const int start = b * 6 + min(b, 192);
    const int cnt_t = 6 + (b < 192 ? 1 : 0);

    // thread -> x-quad: lxg (tid&3)*4, ly (tid>>2)&15, lz tid>>6
    const int lxg = (tid & 3) * 4;
    const int ly  = (tid >> 2) & 15;
    const int lz  = tid >> 6;

    float sq = 0.0f, cntm = 0.0f;

    // ---- prologue: stage tile(start) + its streams ----
    int tx, ty, tz;
    tile_coords(start, tx, ty, tz);
    stage_tile(movh, zbuf, sbufd[0], tx * 16 - 8, ty * 16 - 8, tz * 16 - 8, tid);
    Streams S0 = prefetch_streams(vf, fix, mask,
        ((tz * 16 + lz) * HH + ty * 16 + ly) * WW + tx * 16 + lxg);
    __syncthreads();   // drain DMA(start)

    for (int k = 0; k < cnt_t; ++k) {
        const int cur = k & 1;
        Streams S1 = S0;
        if (k + 1 < cnt_t) {
            int nx, ny, nz;
            tile_coords(start + k + 1, nx, ny, nz);
            stage_tile(movh, zbuf, sbufd[cur ^ 1],
                       nx * 16 - 8, ny * 16 - 8, nz * 16 - 8, tid);
            S1 = prefetch_streams(vf, fix, mask,
                ((nz * 16 + lz) * HH + ny * 16 + ly) * WW + nx * 16 + lxg);
        }

        // ---- compute current tile (DMA for k+1 streams underneath) ----
        int cx, cy, cz;
        tile_coords(start + k, cx, cy, cz);
        const int x_lo = cx * 16 - 8, y_lo = cy * 16 - 8, z_lo = cz * 16 - 8;
        const int gz = cz * 16 + lz, gy = cy * 16 + ly, gx0 = cx * 16 + lxg;
        const uint* sdw = sbufd[cur];

        sample_accum(sdw, mov, gz, gy, gx0,     S0.dz.x, S0.dy.x, S0.dx.x,
                     S0.f.x, S0.m.x, x_lo, y_lo, z_lo, sq, cntm);
        sample_accum(sdw, mov, gz, gy, gx0 + 1, S0.dz.y, S0.dy.y, S0.dx.y,
                     S0.f.y, S0.m.y, x_lo, y_lo, z_lo, sq, cntm);
        sample_accum(sdw, mov, gz, gy, gx0 + 2, S0.dz.z, S0.dy.z, S0.dx.z,
                     S0.f.z, S0.m.z, x_lo, y_lo, z_lo, sq, cntm);
        sample_accum(sdw, mov, gz, gy, gx0 + 3, S0.dz.w, S0.dy.w, S0.dx.w,
                     S0.f.w, S0.m.w, x_lo, y_lo, z_lo, sq, cntm);

        __syncthreads();   // drains DMA(k+1); guards buffer reuse
        S0 = S1;
    }

    // ---- reduction: wave64 shuffle -> LDS -> one atomic pair per block ----
    #pragma unroll
    for (int off = 32; off > 0; off >>= 1) {
        sq   += __shfl_down(sq, off, 64);
        cntm += __shfl_down(cntm, off, 64);
    }
    const int lane = tid & 63;
    const int wid = tid >> 6;
    if (lane == 0) { s_sq[wid] = sq; s_cnt[wid] = cntm; }
    __syncthreads();
    if (tid == 0) {
        float bsq = 0.0f, bcnt = 0.0f;
        #pragma unroll
        for (int i = 0; i < 16; ++i) { bsq += s_sq[i]; bcnt += s_cnt[i]; }
        atomicAdd(&acc[0], bsq);
        atomicAdd(&acc[1], bcnt);
        __threadfence();
        const unsigned old = atomicAdd((unsigned*)&acc[2], 1u);
        if (old == GRID - 1) {
            __threadfence();
            const float s = atomicAdd(&acc[0], 0.0f);
            const float c = atomicAdd(&acc[1], 0.0f);
            out[0] = s / fmaxf(c, 1.0f);
        }
    }
}

// ---- emergency fallback (ws too small): simple per-voxel kernel ----
__global__ __launch_bounds__(256) void warp_mse_simple(
    const float* __restrict__ mov, const float* __restrict__ vf,
    const float* __restrict__ fix, const int* __restrict__ mask,
    float* __restrict__ acc)
{
    const int idx = blockIdx.x * 256 + threadIdx.x;
    float sq = 0.0f, cnt = 0.0f;
    if (idx < NVOX) {
        const int w = idx % WW;
        const int t = idx / WW;
        const int h = t % HH;
        const int d = t / HH;
        const float z = (float)d + vf[idx];
        const float y = (float)h + vf[NVOX + idx];
        const float x = (float)w + vf[2 * NVOX + idx];
        const float z0f = floorf(z), y0f = floorf(y), x0f = floorf(x);
        const float wz = z - z0f, wy = y - y0f, wx = x - x0f;
        const int z0 = (int)z0f, y0 = (int)y0f, x0 = (int)x0f;
        const int z1 = z0 + 1, y1 = y0 + 1, x1 = x0 + 1;
        const bool zi0 = (unsigned)z0 < DD, zi1 = (unsigned)z1 < DD;
        const bool yi0 = (unsigned)y0 < HH, yi1 = (unsigned)y1 < HH;
        const bool xi0 = (unsigned)x0 < WW, xi1 = (unsigned)x1 < WW;
        auto ld = [&](int iz, int iy, int ix, bool ok) -> float {
            return ok ? mov[(iz * HH + iy) * WW + ix] : 0.0f;
        };
        const float v000 = ld(z0, y0, x0, zi0 & yi0 & xi0);
        const float v001 = ld(z0, y0, x1, zi0 & yi0 & xi1);
        const float v010 = ld(z0, y1, x0, zi0 & yi1 & xi0);
        const float v011 = ld(z0, y1, x1, zi0 & yi1 & xi1);
        const float v100 = ld(z1, y0, x0, zi1 & yi0 & xi0);
        const float v101 = ld(z1, y0, x1, zi1 & yi0 & xi1);
        const float v110 = ld(z1, y1, x0, zi1 & yi1 & xi0);
        const float v111 = ld(z1, y1, x1, zi1 & yi1 & xi1);
        const float c00 = v000 + (v001 - v000) * wx;
        const float c01 = v010 + (v011 - v010) * wx;
        const float c10 = v100 + (v101 - v100) * wx;
        const float c11 = v110 + (v111 - v110) * wx;
        const float c0 = c00 + (c01 - c00) * wy;
        const float c1 = c10 + (c11 - c10) * wy;
        const float warped = c0 + (c1 - c0) * wz;
        const float m = (mask[idx] != 0) ? 1.0f : 0.0f;
        const float diff = warped - fix[idx];
        sq = diff * diff * m;
        cnt = m;
    }
    #pragma unroll
    for (int off = 32; off > 0; off >>= 1) {
        sq  += __shfl_down(sq, off, 64);
        cnt += __shfl_down(cnt, off, 64);
    }
    __shared__ float s_sq[4], s_cnt[4];
    const int lane = threadIdx.x & 63, wid = threadIdx.x >> 6;
    if (lane == 0) { s_sq[wid] = sq; s_cnt[wid] = cnt; }
    __syncthreads();
    if (threadIdx.x == 0) {
        atomicAdd(&acc[0], s_sq[0] + s_sq[1] + s_sq[2] + s_sq[3]);
        atomicAdd(&acc[1], s_cnt[0] + s_cnt[1] + s_cnt[2] + s_cnt[3]);
    }
}

__global__ void warp_mse_finalize(const float* __restrict__ acc, float* __restrict__ out) {
    out[0] = acc[0] / fmaxf(acc[1], 1.0f);
}

extern "C" void kernel_launch(void* const* d_in, const int* in_sizes, int n_in,
                              void* d_out, int out_size, void* d_ws, size_t ws_size,
                              hipStream_t stream) {
    const float* mov  = (const float*)d_in[0];
    const float* vf   = (const float*)d_in[1];
    const float* fix  = (const float*)d_in[2];
    const int*   mask = (const int*)d_in[3];
    float* acc = (float*)d_ws;
    float* out = (float*)d_out;

    // [0,16): acc; [64,80): zero DMA source; [256,...): movh
    hipMemsetAsync(d_ws, 0, 256, stream);

    const size_t need = 256 + (size_t)NVOX * 2;
    if (ws_size >= need) {
        ushort* movh = (ushort*)((char*)d_ws + 256);
        const ushort* zbuf = (const ushort*)((char*)d_ws + 64);
        conv_fp16<<<NVOX / (256 * 8), 256, 0, stream>>>(
            (const float4*)mov, (int4*)movh);
        warp_mse_persist<<<GRID, NT, 0, stream>>>(movh, mov, vf, fix, mask,
                                                  zbuf, acc, out);
    } else {
        warp_mse_simple<<<(NVOX + 255) / 256, 256, 0, stream>>>(mov, vf, fix, mask, acc);
        warp_mse_finalize<<<1, 1, 0, stream>>>(acc, out);
    }
}